// Round 1
// baseline (1480.764 us; speedup 1.0000x reference)
//
#include <hip/hip_runtime.h>
#include <hip/hip_bf16.h>

#define N_NODES 50000
#define N_EDGES 600000
#define D 128
#define H2 256
#define TN 16  // nodes per MLP block

// --- Edge stage: aggr[dst] += h[src] + edge_attr -----------------------------
// 32 threads per edge, each thread owns a 4-float chunk of the 128-dim row.
__global__ __launch_bounds__(256) void edge_scatter_kernel(
    const float* __restrict__ h, const float* __restrict__ ea,
    const int* __restrict__ src, const int* __restrict__ dst,
    float* __restrict__ aggr)
{
    unsigned int gid = blockIdx.x * 256u + threadIdx.x;
    unsigned int e = gid >> 5;
    if (e >= N_EDGES) return;
    unsigned int c = (gid & 31u) << 2;   // feature offset 0..124
    int s = src[e];
    int d = dst[e];
    const float4 hv = *(const float4*)(h  + (size_t)s * D + c);
    const float4 ev = *(const float4*)(ea + (size_t)e * D + c);
    float* ap = aggr + (size_t)d * D + c;
    atomicAdd(ap + 0, hv.x + ev.x);
    atomicAdd(ap + 1, hv.y + ev.y);
    atomicAdd(ap + 2, hv.z + ev.z);
    atomicAdd(ap + 3, hv.w + ev.w);
}

// --- Node stage: out = (1+eps)*h + MLP(aggr) --------------------------------
// One block = 16 nodes. GEMM1 (128->256): thread j computes hidden[t][j] for
// all 16 nodes, reusing each W1 element 16x from registers. GEMM2 (256->128):
// thread handles feat i=tid&127 for 8 nodes (g=tid>>7 interleave).
__global__ __launch_bounds__(256) void mlp_kernel(
    const float* __restrict__ aggr, const float* __restrict__ h,
    const float* __restrict__ W1, const float* __restrict__ b1,
    const float* __restrict__ W2, const float* __restrict__ b2,
    const float* __restrict__ eps, float* __restrict__ out)
{
    __shared__ float s_aggr[TN][D];      // 8 KB
    __shared__ float s_hidden[TN][H2];   // 16 KB
    const int tid = threadIdx.x;
    const int node0 = blockIdx.x * TN;

    // Stage aggr rows into LDS (2048 floats = 512 float4; 2 per thread).
    {
        const float4* g4 = (const float4*)(aggr + (size_t)node0 * D);
        float4* s4 = (float4*)(&s_aggr[0][0]);
        #pragma unroll
        for (int i = tid; i < TN * D / 4; i += 256) s4[i] = g4[i];
    }
    __syncthreads();

    // GEMM1 + bias + ReLU
    float acc[TN];
    {
        const float bv = b1[tid];
        #pragma unroll
        for (int t = 0; t < TN; ++t) acc[t] = bv;
    }
    for (int k = 0; k < D; ++k) {
        float w = W1[(size_t)k * H2 + tid];
        #pragma unroll
        for (int t = 0; t < TN; ++t)
            acc[t] = fmaf(s_aggr[t][k], w, acc[t]);
    }
    #pragma unroll
    for (int t = 0; t < TN; ++t)
        s_hidden[t][tid] = fmaxf(acc[t], 0.0f);
    __syncthreads();

    // GEMM2 + bias + residual
    const int i = tid & (D - 1);
    const int g = tid >> 7;  // 0 or 1
    float acc2[TN / 2];
    {
        const float bv = b2[i];
        #pragma unroll
        for (int t = 0; t < TN / 2; ++t) acc2[t] = bv;
    }
    for (int k = 0; k < H2; ++k) {
        float w = W2[(size_t)k * D + i];
        #pragma unroll
        for (int t = 0; t < TN / 2; ++t)
            acc2[t] = fmaf(s_hidden[2 * t + g][k], w, acc2[t]);
    }
    const float ep = 1.0f + eps[0];
    #pragma unroll
    for (int t = 0; t < TN / 2; ++t) {
        int node = node0 + 2 * t + g;
        out[(size_t)node * D + i] = acc2[t] + ep * h[(size_t)node * D + i];
    }
}

extern "C" void kernel_launch(void* const* d_in, const int* in_sizes, int n_in,
                              void* d_out, int out_size, void* d_ws, size_t ws_size,
                              hipStream_t stream) {
    const float* h   = (const float*)d_in[0];
    const float* ea  = (const float*)d_in[1];
    const int*   src = (const int*)d_in[2];
    const int*   dst = (const int*)d_in[3];
    const float* W1  = (const float*)d_in[4];
    const float* b1  = (const float*)d_in[5];
    const float* W2  = (const float*)d_in[6];
    const float* b2  = (const float*)d_in[7];
    const float* eps = (const float*)d_in[8];
    float* out  = (float*)d_out;
    float* aggr = (float*)d_ws;   // N_NODES * D floats = 25.6 MB

    hipMemsetAsync(aggr, 0, (size_t)N_NODES * D * sizeof(float), stream);

    const unsigned int edge_threads = (unsigned int)N_EDGES * 32u;
    edge_scatter_kernel<<<(edge_threads + 255) / 256, 256, 0, stream>>>(
        h, ea, src, dst, aggr);

    mlp_kernel<<<(N_NODES + TN - 1) / TN, 256, 0, stream>>>(
        aggr, h, W1, b1, W2, b2, eps, out);
}

// Round 2
// 724.010 us; speedup vs baseline: 2.0452x; 2.0452x over previous
//
#include <hip/hip_runtime.h>
#include <hip/hip_bf16.h>

#define N_NODES 50000
#define N_EDGES 600000
#define D 128
#define H2 256
#define TN 16  // nodes per fused block (50000/16 = 3125 exactly, no tail)

// ---------------------------------------------------------------------------
// Stage 1: histogram of dst -> counts[50000]
__global__ __launch_bounds__(256) void hist_kernel(const int* __restrict__ dst,
                                                   int* __restrict__ counts) {
    unsigned int e = blockIdx.x * 256u + threadIdx.x;
    if (e < N_EDGES) atomicAdd(&counts[dst[e]], 1);
}

// Stage 2: exclusive scan of counts -> offsets[50001], copy -> cursor[50000].
// Single block, 1024 threads (16 waves), chunked. Wave shuffle scan + tiny
// serial scan of the 16 wave totals.
__global__ __launch_bounds__(1024) void scan_kernel(const int* __restrict__ counts,
                                                    int* __restrict__ offsets,
                                                    int* __restrict__ cursor) {
    __shared__ int wave_sums[16];
    __shared__ int carry_s;
    const int tid = threadIdx.x;
    const int lane = tid & 63;
    const int wv = tid >> 6;
    if (tid == 0) carry_s = 0;
    __syncthreads();
    for (int base = 0; base < N_NODES; base += 1024) {
        const int i = base + tid;
        const int c = (i < N_NODES) ? counts[i] : 0;
        // inclusive wave scan of c
        int x = c;
        #pragma unroll
        for (int d = 1; d < 64; d <<= 1) {
            int t = __shfl_up(x, d, 64);
            if (lane >= d) x += t;
        }
        if (lane == 63) wave_sums[wv] = x;
        __syncthreads();
        if (tid == 0) {  // serial scan of 16 wave totals (inclusive)
            int s = 0;
            #pragma unroll
            for (int w = 0; w < 16; ++w) { s += wave_sums[w]; wave_sums[w] = s; }
        }
        __syncthreads();
        const int prefix = carry_s + (wv > 0 ? wave_sums[wv - 1] : 0) + (x - c);
        if (i < N_NODES) { offsets[i] = prefix; cursor[i] = prefix; }
        __syncthreads();
        if (tid == 0) carry_s += wave_sums[15] - wave_sums[15] + wave_sums[15]; // += chunk total
        __syncthreads();
    }
    if (tid == 0) offsets[N_NODES] = N_EDGES;
}

// Stage 3: scatter edge ids (and src) into dst-sorted order.
__global__ __launch_bounds__(256) void scatter_kernel(const int* __restrict__ src,
                                                      const int* __restrict__ dst,
                                                      int* __restrict__ cursor,
                                                      int2* __restrict__ perm2) {
    unsigned int e = blockIdx.x * 256u + threadIdx.x;
    if (e >= N_EDGES) return;
    const int d = dst[e];
    const int p = atomicAdd(&cursor[d], 1);
    perm2[p] = make_int2((int)e, src[e]);
}

// ---------------------------------------------------------------------------
// Stage 4: fused gather + MLP + residual.
// Block = 16 nodes, 256 threads.
//   Phase A: 8 groups of 32 lanes gather edge lists into s_aggr (2 nodes/group).
//   GEMM1: thread owns 4 j-cols (j0=(tid&63)*4) x 4 nodes (tg=tid>>6).
//   GEMM2: thread owns 4 i-cols (i0=(tid&31)*4) x 2 nodes (g=tid>>5).
__global__ __launch_bounds__(256) void fused_kernel(
    const float* __restrict__ h, const float* __restrict__ ea,
    const int* __restrict__ offsets, const int2* __restrict__ perm2,
    const float* __restrict__ W1, const float* __restrict__ b1,
    const float* __restrict__ W2, const float* __restrict__ b2,
    const float* __restrict__ eps, float* __restrict__ out)
{
    __shared__ float s_aggr[TN][D];     // 8 KB
    __shared__ float s_hidden[TN][H2];  // 16 KB
    const int tid = threadIdx.x;
    const int node0 = blockIdx.x * TN;

    // ---- Phase A: gather ----
    {
        const int grp = tid >> 5;          // 0..7
        const int c = (tid & 31) << 2;     // float offset 0..124
        #pragma unroll
        for (int rep = 0; rep < 2; ++rep) {
            const int t = grp + rep * 8;
            const int node = node0 + t;
            const int beg = offsets[node];
            const int end = offsets[node + 1];
            float4 acc = make_float4(0.f, 0.f, 0.f, 0.f);
            for (int j = beg; j < end; ++j) {
                const int2 p = perm2[j];
                const float4 ev = *(const float4*)(ea + (size_t)p.x * D + c);
                const float4 hv = *(const float4*)(h + (size_t)p.y * D + c);
                acc.x += ev.x + hv.x;
                acc.y += ev.y + hv.y;
                acc.z += ev.z + hv.z;
                acc.w += ev.w + hv.w;
            }
            *(float4*)&s_aggr[t][c] = acc;
        }
    }
    __syncthreads();

    // ---- GEMM1: hidden = relu(aggr @ W1 + b1) ----
    {
        const int j0 = (tid & 63) << 2;    // 0..252
        const int tbase = (tid >> 6) << 2; // 0,4,8,12
        float4 acc1[4];
        const float4 bv = *(const float4*)(b1 + j0);
        #pragma unroll
        for (int t = 0; t < 4; ++t) acc1[t] = bv;
        for (int k = 0; k < D; k += 4) {
            float4 w[4];
            #pragma unroll
            for (int q = 0; q < 4; ++q)
                w[q] = *(const float4*)(W1 + (size_t)(k + q) * H2 + j0);
            #pragma unroll
            for (int t = 0; t < 4; ++t) {
                const float4 a = *(const float4*)&s_aggr[tbase + t][k];
                acc1[t].x = fmaf(a.x, w[0].x, acc1[t].x);
                acc1[t].y = fmaf(a.x, w[0].y, acc1[t].y);
                acc1[t].z = fmaf(a.x, w[0].z, acc1[t].z);
                acc1[t].w = fmaf(a.x, w[0].w, acc1[t].w);
                acc1[t].x = fmaf(a.y, w[1].x, acc1[t].x);
                acc1[t].y = fmaf(a.y, w[1].y, acc1[t].y);
                acc1[t].z = fmaf(a.y, w[1].z, acc1[t].z);
                acc1[t].w = fmaf(a.y, w[1].w, acc1[t].w);
                acc1[t].x = fmaf(a.z, w[2].x, acc1[t].x);
                acc1[t].y = fmaf(a.z, w[2].y, acc1[t].y);
                acc1[t].z = fmaf(a.z, w[2].z, acc1[t].z);
                acc1[t].w = fmaf(a.z, w[2].w, acc1[t].w);
                acc1[t].x = fmaf(a.w, w[3].x, acc1[t].x);
                acc1[t].y = fmaf(a.w, w[3].y, acc1[t].y);
                acc1[t].z = fmaf(a.w, w[3].z, acc1[t].z);
                acc1[t].w = fmaf(a.w, w[3].w, acc1[t].w);
            }
        }
        #pragma unroll
        for (int t = 0; t < 4; ++t) {
            float4 r;
            r.x = fmaxf(acc1[t].x, 0.f);
            r.y = fmaxf(acc1[t].y, 0.f);
            r.z = fmaxf(acc1[t].z, 0.f);
            r.w = fmaxf(acc1[t].w, 0.f);
            *(float4*)&s_hidden[tbase + t][j0] = r;
        }
    }
    __syncthreads();

    // ---- GEMM2 + residual: out = (1+eps)*h + hidden @ W2 + b2 ----
    {
        const int i0 = (tid & 31) << 2;    // 0..124
        const int g = tid >> 5;            // 0..7 -> nodes g, g+8
        float4 acc2[2];
        const float4 bv = *(const float4*)(b2 + i0);
        acc2[0] = bv; acc2[1] = bv;
        for (int k = 0; k < H2; k += 4) {
            float4 w[4];
            #pragma unroll
            for (int q = 0; q < 4; ++q)
                w[q] = *(const float4*)(W2 + (size_t)(k + q) * D + i0);
            #pragma unroll
            for (int u = 0; u < 2; ++u) {
                const float4 a = *(const float4*)&s_hidden[g + u * 8][k];
                acc2[u].x = fmaf(a.x, w[0].x, acc2[u].x);
                acc2[u].y = fmaf(a.x, w[0].y, acc2[u].y);
                acc2[u].z = fmaf(a.x, w[0].z, acc2[u].z);
                acc2[u].w = fmaf(a.x, w[0].w, acc2[u].w);
                acc2[u].x = fmaf(a.y, w[1].x, acc2[u].x);
                acc2[u].y = fmaf(a.y, w[1].y, acc2[u].y);
                acc2[u].z = fmaf(a.y, w[1].z, acc2[u].z);
                acc2[u].w = fmaf(a.y, w[1].w, acc2[u].w);
                acc2[u].x = fmaf(a.z, w[2].x, acc2[u].x);
                acc2[u].y = fmaf(a.z, w[2].y, acc2[u].y);
                acc2[u].z = fmaf(a.z, w[2].z, acc2[u].z);
                acc2[u].w = fmaf(a.z, w[2].w, acc2[u].w);
                acc2[u].x = fmaf(a.w, w[3].x, acc2[u].x);
                acc2[u].y = fmaf(a.w, w[3].y, acc2[u].y);
                acc2[u].z = fmaf(a.w, w[3].z, acc2[u].z);
                acc2[u].w = fmaf(a.w, w[3].w, acc2[u].w);
            }
        }
        const float ep = 1.0f + eps[0];
        #pragma unroll
        for (int u = 0; u < 2; ++u) {
            const int node = node0 + g + u * 8;
            const float4 hv = *(const float4*)(h + (size_t)node * D + i0);
            float4 o;
            o.x = fmaf(ep, hv.x, acc2[u].x);
            o.y = fmaf(ep, hv.y, acc2[u].y);
            o.z = fmaf(ep, hv.z, acc2[u].z);
            o.w = fmaf(ep, hv.w, acc2[u].w);
            *(float4*)(out + (size_t)node * D + i0) = o;
        }
    }
}

extern "C" void kernel_launch(void* const* d_in, const int* in_sizes, int n_in,
                              void* d_out, int out_size, void* d_ws, size_t ws_size,
                              hipStream_t stream) {
    const float* h   = (const float*)d_in[0];
    const float* ea  = (const float*)d_in[1];
    const int*   src = (const int*)d_in[2];
    const int*   dst = (const int*)d_in[3];
    const float* W1  = (const float*)d_in[4];
    const float* b1  = (const float*)d_in[5];
    const float* W2  = (const float*)d_in[6];
    const float* b2  = (const float*)d_in[7];
    const float* eps = (const float*)d_in[8];
    float* out = (float*)d_out;

    char* ws = (char*)d_ws;
    int*  counts  = (int*)ws;                      // 200 KB
    int*  offsets = (int*)(ws + 256 * 1024);       // 200 KB (+1)
    int*  cursor  = (int*)(ws + 512 * 1024);       // 200 KB
    int2* perm2   = (int2*)(ws + 1024 * 1024);     // 4.8 MB

    hipMemsetAsync(counts, 0, N_NODES * sizeof(int), stream);

    const int eblocks = (N_EDGES + 255) / 256;
    hist_kernel<<<eblocks, 256, 0, stream>>>(dst, counts);
    scan_kernel<<<1, 1024, 0, stream>>>(counts, offsets, cursor);
    scatter_kernel<<<eblocks, 256, 0, stream>>>(src, dst, cursor, perm2);
    fused_kernel<<<N_NODES / TN, 256, 0, stream>>>(
        h, ea, offsets, perm2, W1, b1, W2, b2, eps, out);
}

// Round 3
// 661.194 us; speedup vs baseline: 2.2395x; 1.0950x over previous
//
#include <hip/hip_runtime.h>
#include <hip/hip_bf16.h>

#define N_NODES 50000
#define N_EDGES 600000
#define D 128
#define H2 256
#define TN 16      // nodes per fused block (50000/16 = 3125 exactly)
#define MAXC 2048  // perm chunk capacity in LDS (aliases s_hidden: 16KB = 2048 int2)

// ---------------------------------------------------------------------------
// Stage 1: histogram of dst -> counts[50000]
__global__ __launch_bounds__(256) void hist_kernel(const int* __restrict__ dst,
                                                   int* __restrict__ counts) {
    unsigned int e = blockIdx.x * 256u + threadIdx.x;
    if (e < N_EDGES) atomicAdd(&counts[dst[e]], 1);
}

// Stage 2a: block-local exclusive scan (196 blocks x 256 threads)
__global__ __launch_bounds__(256) void scan1_kernel(const int* __restrict__ counts,
                                                    int* __restrict__ scanned,
                                                    int* __restrict__ blocksums) {
    __shared__ int wsum[4];
    const int tid = threadIdx.x;
    const int lane = tid & 63;
    const int wv = tid >> 6;
    const int i = blockIdx.x * 256 + tid;
    const int cval = (i < N_NODES) ? counts[i] : 0;
    int x = cval;
    #pragma unroll
    for (int d = 1; d < 64; d <<= 1) {
        int t = __shfl_up(x, d, 64);
        if (lane >= d) x += t;
    }
    if (lane == 63) wsum[wv] = x;
    __syncthreads();
    if (tid == 0) {
        int s = 0;
        #pragma unroll
        for (int w = 0; w < 4; ++w) { s += wsum[w]; wsum[w] = s; }
    }
    __syncthreads();
    const int prefix = (wv > 0 ? wsum[wv - 1] : 0) + (x - cval);
    if (i < N_NODES) scanned[i] = prefix;
    if (tid == 0) blocksums[blockIdx.x] = wsum[3];
}

// Stage 2b: exclusive scan of the 196 block sums (1 block, 256 threads)
__global__ __launch_bounds__(256) void scan2_kernel(const int* __restrict__ blocksums,
                                                    int* __restrict__ blockbase, int nb) {
    __shared__ int wsum[4];
    const int tid = threadIdx.x;
    const int lane = tid & 63;
    const int wv = tid >> 6;
    const int cval = (tid < nb) ? blocksums[tid] : 0;
    int x = cval;
    #pragma unroll
    for (int d = 1; d < 64; d <<= 1) {
        int t = __shfl_up(x, d, 64);
        if (lane >= d) x += t;
    }
    if (lane == 63) wsum[wv] = x;
    __syncthreads();
    if (tid == 0) {
        int s = 0;
        #pragma unroll
        for (int w = 0; w < 4; ++w) { s += wsum[w]; wsum[w] = s; }
    }
    __syncthreads();
    if (tid < nb) blockbase[tid] = (wv > 0 ? wsum[wv - 1] : 0) + (x - cval);
}

// Stage 2c: add block bases -> offsets, prime cursor
__global__ __launch_bounds__(256) void scan3_kernel(const int* __restrict__ scanned,
                                                    const int* __restrict__ blockbase,
                                                    int* __restrict__ offsets,
                                                    int* __restrict__ cursor) {
    const int i = blockIdx.x * 256 + threadIdx.x;
    if (i < N_NODES) {
        const int v = scanned[i] + blockbase[blockIdx.x];
        offsets[i] = v;
        cursor[i] = v;
    }
    if (i == 0) offsets[N_NODES] = N_EDGES;
}

// Stage 3: scatter edges into dst-sorted order. Pack local node id (dst&15)
// into bits 20..23 of .x (edge id < 600000 < 2^20).
__global__ __launch_bounds__(256) void scatter_kernel(const int* __restrict__ src,
                                                      const int* __restrict__ dst,
                                                      int* __restrict__ cursor,
                                                      int2* __restrict__ perm2) {
    unsigned int e = blockIdx.x * 256u + threadIdx.x;
    if (e >= N_EDGES) return;
    const int d = dst[e];
    const int p = atomicAdd(&cursor[d], 1);
    perm2[p] = make_int2((int)e | ((d & (TN - 1)) << 20), src[e]);
}

// ---------------------------------------------------------------------------
// Stage 4: fused gather + MLP + residual. Block = 16 nodes, 256 threads.
__global__ __launch_bounds__(256) void fused_kernel(
    const float* __restrict__ h, const float* __restrict__ ea,
    const int* __restrict__ offsets, const int2* __restrict__ perm2,
    const float* __restrict__ W1, const float* __restrict__ b1,
    const float* __restrict__ W2, const float* __restrict__ b2,
    const float* __restrict__ eps, float* __restrict__ out)
{
    __shared__ float s_aggr[TN][D];     // 8 KB
    __shared__ float s_hidden[TN][H2];  // 16 KB (phase A: aliased as perm staging)
    int2* s_perm = (int2*)&s_hidden[0][0];

    const int tid = threadIdx.x;
    const int node0 = blockIdx.x * TN;

    // zero s_aggr
    for (int i = tid; i < TN * D / 4; i += 256)
        ((float4*)s_aggr)[i] = make_float4(0.f, 0.f, 0.f, 0.f);

    const int beg = offsets[node0];
    const int end = offsets[node0 + TN];
    const int grp = tid >> 5;        // 0..7
    const int c = (tid & 31) << 2;   // float offset 0..124

    for (int cb = beg; cb < end; cb += MAXC) {
        const int cnt = min(end - cb, MAXC);
        __syncthreads();  // s_aggr zero done / prior s_perm use done
        for (int i = tid; i < cnt; i += 256) s_perm[i] = perm2[cb + i];
        __syncthreads();
        // contiguous sub-range per 32-lane group -> concurrent edges hit
        // different dst nodes; register accumulate, flush on dst change.
        const int per = (cnt + 7) >> 3;
        const int lo = grp * per;
        const int hi = min(lo + per, cnt);
        float4 acc = make_float4(0.f, 0.f, 0.f, 0.f);
        int tcur = -1;
        for (int j = lo; j < hi; ++j) {
            const int2 p = s_perm[j];
            const int t = p.x >> 20;
            const int e = p.x & 0xFFFFF;
            const float4 ev = *(const float4*)(ea + (size_t)e * D + c);
            const float4 hv = *(const float4*)(h + (size_t)p.y * D + c);
            if (t != tcur) {
                if (tcur >= 0) {
                    atomicAdd(&s_aggr[tcur][c + 0], acc.x);
                    atomicAdd(&s_aggr[tcur][c + 1], acc.y);
                    atomicAdd(&s_aggr[tcur][c + 2], acc.z);
                    atomicAdd(&s_aggr[tcur][c + 3], acc.w);
                }
                acc = make_float4(0.f, 0.f, 0.f, 0.f);
                tcur = t;
            }
            acc.x += ev.x + hv.x;
            acc.y += ev.y + hv.y;
            acc.z += ev.z + hv.z;
            acc.w += ev.w + hv.w;
        }
        if (tcur >= 0) {
            atomicAdd(&s_aggr[tcur][c + 0], acc.x);
            atomicAdd(&s_aggr[tcur][c + 1], acc.y);
            atomicAdd(&s_aggr[tcur][c + 2], acc.z);
            atomicAdd(&s_aggr[tcur][c + 3], acc.w);
        }
    }
    __syncthreads();

    // ---- GEMM1: hidden = relu(aggr @ W1 + b1) ----
    {
        const int j0 = (tid & 63) << 2;    // 0..252
        const int tbase = (tid >> 6) << 2; // 0,4,8,12
        float4 acc1[4];
        const float4 bv = *(const float4*)(b1 + j0);
        #pragma unroll
        for (int t = 0; t < 4; ++t) acc1[t] = bv;
        for (int k = 0; k < D; k += 4) {
            float4 w[4];
            #pragma unroll
            for (int q = 0; q < 4; ++q)
                w[q] = *(const float4*)(W1 + (size_t)(k + q) * H2 + j0);
            #pragma unroll
            for (int t = 0; t < 4; ++t) {
                const float4 a = *(const float4*)&s_aggr[tbase + t][k];
                acc1[t].x = fmaf(a.x, w[0].x, acc1[t].x);
                acc1[t].y = fmaf(a.x, w[0].y, acc1[t].y);
                acc1[t].z = fmaf(a.x, w[0].z, acc1[t].z);
                acc1[t].w = fmaf(a.x, w[0].w, acc1[t].w);
                acc1[t].x = fmaf(a.y, w[1].x, acc1[t].x);
                acc1[t].y = fmaf(a.y, w[1].y, acc1[t].y);
                acc1[t].z = fmaf(a.y, w[1].z, acc1[t].z);
                acc1[t].w = fmaf(a.y, w[1].w, acc1[t].w);
                acc1[t].x = fmaf(a.z, w[2].x, acc1[t].x);
                acc1[t].y = fmaf(a.z, w[2].y, acc1[t].y);
                acc1[t].z = fmaf(a.z, w[2].z, acc1[t].z);
                acc1[t].w = fmaf(a.z, w[2].w, acc1[t].w);
                acc1[t].x = fmaf(a.w, w[3].x, acc1[t].x);
                acc1[t].y = fmaf(a.w, w[3].y, acc1[t].y);
                acc1[t].z = fmaf(a.w, w[3].z, acc1[t].z);
                acc1[t].w = fmaf(a.w, w[3].w, acc1[t].w);
            }
        }
        __syncthreads();  // all reads of s_perm (aliased) done before hidden write
        #pragma unroll
        for (int t = 0; t < 4; ++t) {
            float4 r;
            r.x = fmaxf(acc1[t].x, 0.f);
            r.y = fmaxf(acc1[t].y, 0.f);
            r.z = fmaxf(acc1[t].z, 0.f);
            r.w = fmaxf(acc1[t].w, 0.f);
            *(float4*)&s_hidden[tbase + t][j0] = r;
        }
    }
    __syncthreads();

    // ---- GEMM2 + residual ----
    {
        const int i0 = (tid & 31) << 2;    // 0..124
        const int g = tid >> 5;            // 0..7 -> nodes g, g+8
        float4 acc2[2];
        const float4 bv = *(const float4*)(b2 + i0);
        acc2[0] = bv; acc2[1] = bv;
        for (int k = 0; k < H2; k += 4) {
            float4 w[4];
            #pragma unroll
            for (int q = 0; q < 4; ++q)
                w[q] = *(const float4*)(W2 + (size_t)(k + q) * D + i0);
            #pragma unroll
            for (int u = 0; u < 2; ++u) {
                const float4 a = *(const float4*)&s_hidden[g + u * 8][k];
                acc2[u].x = fmaf(a.x, w[0].x, acc2[u].x);
                acc2[u].y = fmaf(a.x, w[0].y, acc2[u].y);
                acc2[u].z = fmaf(a.x, w[0].z, acc2[u].z);
                acc2[u].w = fmaf(a.x, w[0].w, acc2[u].w);
                acc2[u].x = fmaf(a.y, w[1].x, acc2[u].x);
                acc2[u].y = fmaf(a.y, w[1].y, acc2[u].y);
                acc2[u].z = fmaf(a.y, w[1].z, acc2[u].z);
                acc2[u].w = fmaf(a.y, w[1].w, acc2[u].w);
                acc2[u].x = fmaf(a.z, w[2].x, acc2[u].x);
                acc2[u].y = fmaf(a.z, w[2].y, acc2[u].y);
                acc2[u].z = fmaf(a.z, w[2].z, acc2[u].z);
                acc2[u].w = fmaf(a.z, w[2].w, acc2[u].w);
                acc2[u].x = fmaf(a.w, w[3].x, acc2[u].x);
                acc2[u].y = fmaf(a.w, w[3].y, acc2[u].y);
                acc2[u].z = fmaf(a.w, w[3].z, acc2[u].z);
                acc2[u].w = fmaf(a.w, w[3].w, acc2[u].w);
            }
        }
        const float ep = 1.0f + eps[0];
        #pragma unroll
        for (int u = 0; u < 2; ++u) {
            const int node = node0 + g + u * 8;
            const float4 hv = *(const float4*)(h + (size_t)node * D + i0);
            float4 o;
            o.x = fmaf(ep, hv.x, acc2[u].x);
            o.y = fmaf(ep, hv.y, acc2[u].y);
            o.z = fmaf(ep, hv.z, acc2[u].z);
            o.w = fmaf(ep, hv.w, acc2[u].w);
            *(float4*)(out + (size_t)node * D + i0) = o;
        }
    }
}

extern "C" void kernel_launch(void* const* d_in, const int* in_sizes, int n_in,
                              void* d_out, int out_size, void* d_ws, size_t ws_size,
                              hipStream_t stream) {
    const float* h   = (const float*)d_in[0];
    const float* ea  = (const float*)d_in[1];
    const int*   src = (const int*)d_in[2];
    const int*   dst = (const int*)d_in[3];
    const float* W1  = (const float*)d_in[4];
    const float* b1  = (const float*)d_in[5];
    const float* W2  = (const float*)d_in[6];
    const float* b2  = (const float*)d_in[7];
    const float* eps = (const float*)d_in[8];
    float* out = (float*)d_out;

    char* ws = (char*)d_ws;
    int*  counts    = (int*)ws;                    // 200 KB
    int*  scanned   = (int*)(ws + 256 * 1024);     // 200 KB
    int*  offsets   = (int*)(ws + 512 * 1024);     // 200 KB (+1)
    int*  cursor    = (int*)(ws + 768 * 1024);     // 200 KB
    int*  blocksums = (int*)(ws + 1008 * 1024);    // 1 KB
    int*  blockbase = (int*)(ws + 1012 * 1024);    // 1 KB
    int2* perm2     = (int2*)(ws + 1024 * 1024);   // 4.8 MB

    hipMemsetAsync(counts, 0, N_NODES * sizeof(int), stream);

    const int eblocks = (N_EDGES + 255) / 256;     // 2344
    const int nblocks = (N_NODES + 255) / 256;     // 196

    hist_kernel<<<eblocks, 256, 0, stream>>>(dst, counts);
    scan1_kernel<<<nblocks, 256, 0, stream>>>(counts, scanned, blocksums);
    scan2_kernel<<<1, 256, 0, stream>>>(blocksums, blockbase, nblocks);
    scan3_kernel<<<nblocks, 256, 0, stream>>>(scanned, blockbase, offsets, cursor);
    scatter_kernel<<<eblocks, 256, 0, stream>>>(src, dst, cursor, perm2);
    fused_kernel<<<N_NODES / TN, 256, 0, stream>>>(
        h, ea, offsets, perm2, W1, b1, W2, b2, eps, out);
}